// Round 9
// baseline (386.829 us; speedup 1.0000x reference)
//
#include <hip/hip_runtime.h>
#include <math.h>

// Problem constants (B,H,W,C = 16,32,32,512; 32 groups)
#define BATCH 16
#define NTOK  1024
#define CH    512
#define NGRP  32
#define GSZ   16
#define EPSV  1e-3f
#define MTOT  (BATCH*NTOK)          // 16384
#define SCALE 0.04419417382415922f  // 512^-0.5
#define SEXP  (SCALE*1.4426950408889634f)   // scale*log2(e), for exp2

typedef unsigned short u16;
typedef __attribute__((ext_vector_type(4))) float f32x4;
typedef __attribute__((ext_vector_type(8))) short s16x8;

__device__ __forceinline__ u16 f2bf(float f) {           // RNE float->bf16
    union { float f; unsigned u; } x{f};
    unsigned r = x.u + 0x7fff + ((x.u >> 16) & 1);
    return (u16)(r >> 16);
}

__device__ __forceinline__ void gld16(const u16* g, u16* l) {
    __builtin_amdgcn_global_load_lds(
        (const __attribute__((address_space(1))) void*)g,
        (__attribute__((address_space(3))) void*)l, 16, 0, 0);
}

#define MFMA16 __builtin_amdgcn_mfma_f32_16x16x32_bf16

// ---------------------------------------------------------------- group-norm stats
__global__ __launch_bounds__(256) void gn_stats(const float* __restrict__ x,
                                                float2* __restrict__ stats) {
    int bg = blockIdx.x;             // batch*32 + group
    int b = bg >> 5, g = bg & 31;
    const float* base = x + (size_t)b * NTOK * CH + g * GSZ;
    float s = 0.f, ss = 0.f;
    for (int i = threadIdx.x; i < 4096; i += 256) {
        int p = i >> 2, c4 = i & 3;
        float4 v = *(const float4*)(base + (size_t)p * CH + c4 * 4);
        s  += v.x + v.y + v.z + v.w;
        ss += v.x * v.x + v.y * v.y + v.z * v.z + v.w * v.w;
    }
    for (int off = 32; off; off >>= 1) {
        s  += __shfl_down(s, off);
        ss += __shfl_down(ss, off);
    }
    __shared__ float2 part[4];
    if ((threadIdx.x & 63) == 0) part[threadIdx.x >> 6] = make_float2(s, ss);
    __syncthreads();
    if (threadIdx.x == 0) {
        float S = 0.f, SS = 0.f;
        for (int i = 0; i < 4; i++) { S += part[i].x; SS += part[i].y; }
        float mean = S * (1.f / 16384.f);
        float var  = SS * (1.f / 16384.f) - mean * mean;
        stats[bg] = make_float2(mean, rsqrtf(var + EPSV));
    }
}

// ---------------------------------------------------------------- apply norm -> xn(f32) + xnb(bf16)
__global__ __launch_bounds__(256) void gn_apply(const float* __restrict__ x,
                                                const float2* __restrict__ stats,
                                                const float* __restrict__ gamma,
                                                const float* __restrict__ beta,
                                                float* __restrict__ xn,
                                                u16* __restrict__ xnb) {
    size_t total = (size_t)MTOT * CH / 4;
    for (size_t i4 = (size_t)blockIdx.x * 256 + threadIdx.x; i4 < total;
         i4 += (size_t)gridDim.x * 256) {
        size_t flat = i4 * 4;
        int c = (int)(flat & (CH - 1));
        int b = (int)(flat >> 19);
        int g = c >> 4;
        float2 st = stats[(b << 5) + g];
        float4 xv = *(const float4*)(x + flat);
        float4 gv = *(const float4*)(gamma + c);
        float4 bv = *(const float4*)(beta + c);
        float4 o;
        o.x = (xv.x - st.x) * st.y * gv.x + bv.x;
        o.y = (xv.y - st.x) * st.y * gv.y + bv.y;
        o.z = (xv.z - st.x) * st.y * gv.z + bv.z;
        o.w = (xv.w - st.x) * st.y * gv.w + bv.w;
        *(float4*)(xn + flat) = o;
        uint2 h;
        h.x = (unsigned)f2bf(o.x) | ((unsigned)f2bf(o.y) << 16);
        h.y = (unsigned)f2bf(o.z) | ((unsigned)f2bf(o.w) << 16);
        *(uint2*)(xnb + flat) = h;
    }
}

// ---------------------------------------------------------------- weights: transpose f32->bf16, all 4 in one dispatch
__global__ __launch_bounds__(256) void weights_prep(
    const float* __restrict__ Wq, const float* __restrict__ Wk,
    const float* __restrict__ Wv, const float* __restrict__ Wp,
    u16* __restrict__ WTqkv, u16* __restrict__ WTp) {
    int z = blockIdx.z;
    const float* src = z == 0 ? Wq : z == 1 ? Wk : z == 2 ? Wv : Wp;
    u16* dst = z < 3 ? WTqkv + (size_t)z * CH * CH : WTp;
    __shared__ u16 tile[64][66];
    int r0 = blockIdx.y * 64, c0 = blockIdx.x * 64;
    int t = threadIdx.x;
    for (int i = 0; i < 16; i++) {
        int idx = i * 256 + t;
        int r = idx >> 6, c = idx & 63;
        tile[r][c] = f2bf(src[(size_t)(r0 + r) * CH + c0 + c]);
    }
    __syncthreads();
    for (int i = 0; i < 16; i++) {
        int idx = i * 256 + t;
        int oc = idx >> 6, orr = idx & 63;
        dst[(size_t)(c0 + oc) * CH + r0 + orr] = tile[orr][oc];
    }
}

// bias concat [bq|bk|bv] -> bqkv[1536]
__global__ void prep_bias(const float* __restrict__ bq, const float* __restrict__ bk,
                          const float* __restrict__ bv, float* __restrict__ bqkv) {
    int t = blockIdx.x * 256 + threadIdx.x;   // 0..1535
    bqkv[t] = t < 512 ? bq[t] : (t < 1024 ? bk[t - 512] : bv[t - 1024]);
}

// ---------------------------------------------------------------- V slice -> V^T per batch (bf16)
__global__ __launch_bounds__(256) void vt_transpose(const u16* __restrict__ in,
                                                    u16* __restrict__ out,
                                                    int R, int C, int ldIn,
                                                    long sIn, long sOut) {
    __shared__ u16 tile[64][66];
    int z = blockIdx.z;
    in  += (size_t)z * sIn;
    out += (size_t)z * sOut;
    int r0 = blockIdx.y * 64, c0 = blockIdx.x * 64;
    int t = threadIdx.x;
    for (int i = 0; i < 16; i++) {
        int idx = i * 256 + t;
        int r = idx >> 6, c = idx & 63;
        tile[r][c] = in[(size_t)(r0 + r) * ldIn + c0 + c];
    }
    __syncthreads();
    for (int i = 0; i < 16; i++) {
        int idx = i * 256 + t;
        int oc = idx >> 6, orr = idx & 63;
        out[(size_t)(c0 + oc) * R + r0 + orr] = tile[orr][oc];
    }
}

// ---------------------------------------------------------------- bf16 MFMA GEMM  (C = alpha*A*B^T (+bias) (+res))
// 128x128 tile, 4 waves, dbuf LDS, 2-phase. Chunked XCD swizzle (nb % 8 == 0).
template <bool BIAS, bool RES, bool OUTF32>
__global__ __launch_bounds__(256) void gemm_bt(
    const u16* __restrict__ A, const u16* __restrict__ B, void* __restrict__ Cout,
    const float* __restrict__ bias, const float* __restrict__ res,
    int K, int lda, int ldb, int ldc,
    long sA, long sB, long sC, float alpha) {
    __shared__ __align__(16) u16 Asm[8192];   // 2 x 8 KB
    __shared__ __align__(16) u16 Bsm[8192];

    unsigned flat = blockIdx.x + gridDim.x * (blockIdx.y + gridDim.y * blockIdx.z);
    unsigned nb = gridDim.x * gridDim.y * gridDim.z;
    unsigned lf = (flat & 7) * (nb >> 3) + (flat >> 3);
    unsigned pb = gridDim.x * gridDim.y;
    unsigned bz = lf / pb, rem = lf - bz * pb;
    unsigned by = rem / gridDim.x, bx = rem - by * gridDim.x;

    A += (size_t)bz * sA;
    B += (size_t)bz * sB;
    size_t zc = (size_t)bz * sC;

    int t = threadIdx.x;
    int wave = t >> 6, lane = t & 63;
    int wm = wave >> 1, wn = wave & 1;
    int rowA0 = by * 128;
    int colB0 = bx * 128;

    int c16log = (lane & 3) ^ ((lane >> 3) & 3);     // pre-swizzled global source
    const u16* aG[2]; const u16* bG[2]; u16* aL[2]; u16* bL[2];
#pragma unroll
    for (int j = 0; j < 2; j++) {
        int s = wave * 2 + j;
        int row = s * 16 + (lane >> 2);
        aL[j] = Asm + s * 512;
        bL[j] = Bsm + s * 512;
        aG[j] = A + (size_t)(rowA0 + row) * lda + c16log * 8;
        bG[j] = B + (size_t)(colB0 + row) * ldb + c16log * 8;
    }

    int kg = lane >> 4;
    int aoff[4], boff[4];
#pragma unroll
    for (int i = 0; i < 4; i++) {
        int ra = wm * 64 + i * 16 + (lane & 15);
        aoff[i] = ra * 32 + (kg ^ ((ra >> 1) & 3)) * 8;
        int rb = wn * 64 + i * 16 + (lane & 15);
        boff[i] = rb * 32 + (kg ^ ((rb >> 1) & 3)) * 8;
    }

#define STG_G(buf, ktE)                          \
    {                                            \
        gld16(aG[0] + (ktE), aL[0] + (buf) * 4096); \
        gld16(aG[1] + (ktE), aL[1] + (buf) * 4096); \
        gld16(bG[0] + (ktE), bL[0] + (buf) * 4096); \
        gld16(bG[1] + (ktE), bL[1] + (buf) * 4096); \
    }

    f32x4 acc[4][4] = {};
    int nk = K >> 5;
    STG_G(0, 0);
    __syncthreads();
    for (int kt = 0; kt < nk; kt++) {
        if (kt + 1 < nk) STG_G((kt + 1) & 1, (kt + 1) * 32);
        const u16* as = Asm + (kt & 1) * 4096;
        const u16* bs = Bsm + (kt & 1) * 4096;
        s16x8 af[4], bfr[4];
#pragma unroll
        for (int i = 0; i < 4; i++) {
            af[i]  = *(const s16x8*)(as + aoff[i]);
            bfr[i] = *(const s16x8*)(bs + boff[i]);
        }
#pragma unroll
        for (int mi = 0; mi < 4; mi++)
#pragma unroll
            for (int nj = 0; nj < 4; nj++)
                acc[mi][nj] = MFMA16(af[mi], bfr[nj], acc[mi][nj], 0, 0, 0);
        __syncthreads();
    }
#undef STG_G

    int r0 = rowA0 + wm * 64 + (lane >> 4) * 4;
    int c0c = colB0 + wn * 64 + (lane & 15);
#pragma unroll
    for (int mi = 0; mi < 4; mi++) {
#pragma unroll
        for (int nj = 0; nj < 4; nj++) {
            int c = c0c + nj * 16;
            float bv = BIAS ? bias[c] : 0.f;
            f32x4 v = acc[mi][nj];
#pragma unroll
            for (int j = 0; j < 4; j++) {
                int rr = r0 + mi * 16 + j;
                float val = v[j] * alpha + bv;
                if (RES) val += res[(size_t)rr * ldc + c];
                if (OUTF32) ((float*)Cout)[zc + (size_t)rr * ldc + c] = val;
                else        ((u16*)Cout)[zc + (size_t)rr * ldc + c] = f2bf(val);
            }
        }
    }
}

// ---------------------------------------------------------------- fused flash attention (no-staging, 16 waves)
// One block per (batch, 32-row q-tile); 512 blocks x 1024 thr = 16 col-team waves.
// Per wave: 32 q-rows x 64 k-cols (QK^T), then 32 q-rows x 32 channels (PV).
// K/Q/V fragments read directly from global (L2-resident); zero barriers in loops.
// Register budget: acc1 32 + acc2 16 + ptrs ~16 -> fits 128 VGPR (launch_bounds 1024,4),
// NO spill (r8 lesson: 8-wave variant needed ~130 VGPR and spilled at the 64-cap).
__global__ __launch_bounds__(1024, 4) void attn_fused(const u16* __restrict__ qkv,
                                                      const u16* __restrict__ vtg,
                                                      u16* __restrict__ ao) {
    __shared__ __align__(16) u16 S[32768];       // 64 KB: P tile (+ reduce overlay)

    unsigned flat = blockIdx.x;                  // 512 blocks
    unsigned lf = (flat & 7) * 64 + (flat >> 3); // XCD-chunked: 64 blocks (2 batches)/XCD
    int b = lf >> 5, mt = lf & 31;

    int t = threadIdx.x, w = t >> 6, lane = t & 63;
    int ct = w;                                  // col-team 0..15 (64 k-cols each)
    int l15 = lane & 15, kg = lane >> 4;

    // Q frag pointers: rows mt*32 + rg*16 + l15 (same for all waves -> L1 broadcast)
    const u16* qp[2];
#pragma unroll
    for (int rg = 0; rg < 2; rg++)
        qp[rg] = qkv + (size_t)(b * NTOK + mt * 32 + rg * 16 + l15) * 1536 + kg * 8;
    // K frag pointers: rows ct*64 + nj*16 + l15 (K slice at +CH)
    const u16* kp[4];
#pragma unroll
    for (int nj = 0; nj < 4; nj++)
        kp[nj] = qkv + (size_t)(b * NTOK + ct * 64 + nj * 16 + l15) * 1536 + CH + kg * 8;

    f32x4 acc1[2][4];
#pragma unroll
    for (int rg = 0; rg < 2; rg++)
#pragma unroll
        for (int nj = 0; nj < 4; nj++) acc1[rg][nj] = f32x4{0.f, 0.f, 0.f, 0.f};

#pragma unroll
    for (int kt = 0; kt < 16; kt++) {
        s16x8 a0 = *(const s16x8*)(qp[0] + kt * 32);
        s16x8 a1 = *(const s16x8*)(qp[1] + kt * 32);
        __builtin_amdgcn_s_setprio(1);
#pragma unroll
        for (int nj = 0; nj < 4; nj++) {
            s16x8 bf = *(const s16x8*)(kp[nj] + kt * 32);
            acc1[0][nj] = MFMA16(a0, bf, acc1[0][nj], 0, 0, 0);
            acc1[1][nj] = MFMA16(a1, bf, acc1[1][nj], 0, 0, 0);
        }
        __builtin_amdgcn_s_setprio(0);
    }

    // ---- softmax over full 1024 cols (16 col-teams; scale folded into exp2) ----
    float* redm = (float*)S;          // [32][16]
    float* reds = redm + 512;         // [32][16]
    float mr[2][4], iv[2][4];
#pragma unroll
    for (int rg = 0; rg < 2; rg++)
#pragma unroll
        for (int j = 0; j < 4; j++) {
            float m = acc1[rg][0][j];
#pragma unroll
            for (int nj = 1; nj < 4; nj++) m = fmaxf(m, acc1[rg][nj][j]);
            for (int off = 1; off < 16; off <<= 1) m = fmaxf(m, __shfl_xor(m, off));
            mr[rg][j] = m;
        }
    if (l15 == 0) {
#pragma unroll
        for (int rg = 0; rg < 2; rg++)
#pragma unroll
            for (int j = 0; j < 4; j++)
                redm[(rg * 16 + kg * 4 + j) * 16 + ct] = mr[rg][j];
    }
    __syncthreads();
#pragma unroll
    for (int rg = 0; rg < 2; rg++)
#pragma unroll
        for (int j = 0; j < 4; j++) {
            int row = rg * 16 + kg * 4 + j;
            float m = redm[row * 16];
#pragma unroll
            for (int q = 1; q < 16; q++) m = fmaxf(m, redm[row * 16 + q]);
            mr[rg][j] = m;
        }
#pragma unroll
    for (int rg = 0; rg < 2; rg++)
#pragma unroll
        for (int j = 0; j < 4; j++) {
            float s = 0.f;
#pragma unroll
            for (int nj = 0; nj < 4; nj++) {
                float e = exp2f((acc1[rg][nj][j] - mr[rg][j]) * SEXP);
                acc1[rg][nj][j] = e;
                s += e;
            }
            for (int off = 1; off < 16; off <<= 1) s += __shfl_xor(s, off);
            if (l15 == 0) reds[(rg * 16 + kg * 4 + j) * 16 + ct] = s;
        }
    __syncthreads();
#pragma unroll
    for (int rg = 0; rg < 2; rg++)
#pragma unroll
        for (int j = 0; j < 4; j++) {
            int row = rg * 16 + kg * 4 + j;
            float s = reds[row * 16];
#pragma unroll
            for (int q = 1; q < 16; q++) s += reds[row * 16 + q];
            iv[rg][j] = 1.f / s;
        }
    __syncthreads();   // reduce reads done before pack overwrites S

    // ---- pack P into S: u16 idx = row*1024 + ((g ^ (row&7))<<3) + (k&7), g=k>>3 ----
#pragma unroll
    for (int rg = 0; rg < 2; rg++)
#pragma unroll
        for (int nj = 0; nj < 4; nj++) {
            int k = ct * 64 + nj * 16 + l15;
            int g = k >> 3, ko = k & 7;
#pragma unroll
            for (int j = 0; j < 4; j++) {
                int row = rg * 16 + kg * 4 + j;
                S[row * 1024 + ((g ^ (row & 7)) << 3) + ko] =
                    f2bf(acc1[rg][nj][j] * iv[rg][j]);
            }
        }
    __syncthreads();

    // ---- PV: pa from LDS, V^T frags from global (L2). No barriers in loop. ----
    f32x4 acc2[2][2];
#pragma unroll
    for (int rg = 0; rg < 2; rg++)
#pragma unroll
        for (int cj = 0; cj < 2; cj++) acc2[rg][cj] = f32x4{0.f, 0.f, 0.f, 0.f};

    const u16* vp[2];
#pragma unroll
    for (int cj = 0; cj < 2; cj++)
        vp[cj] = vtg + (size_t)(b * 512 + ct * 32 + cj * 16 + l15) * 1024 + kg * 8;

#pragma unroll 4
    for (int c = 0; c < 32; c++) {
        s16x8 pa0 = *(const s16x8*)(S + (size_t)l15 * 1024 +
                                    (((c * 4 + kg) ^ (l15 & 7)) << 3));
        s16x8 pa1 = *(const s16x8*)(S + (size_t)(16 + l15) * 1024 +
                                    (((c * 4 + kg) ^ (l15 & 7)) << 3));
        __builtin_amdgcn_s_setprio(1);
#pragma unroll
        for (int cj = 0; cj < 2; cj++) {
            s16x8 vf = *(const s16x8*)(vp[cj] + c * 32);
            acc2[0][cj] = MFMA16(pa0, vf, acc2[0][cj], 0, 0, 0);
            acc2[1][cj] = MFMA16(pa1, vf, acc2[1][cj], 0, 0, 0);
        }
        __builtin_amdgcn_s_setprio(0);
    }

    // ---- epilogue: repack acc2 through S (granule-swizzled) -> coalesced uint4 stores ----
    __syncthreads();   // P reads done before overwrite
#pragma unroll
    for (int rg = 0; rg < 2; rg++)
#pragma unroll
        for (int cj = 0; cj < 2; cj++)
#pragma unroll
            for (int j = 0; j < 4; j++) {
                int row = rg * 16 + kg * 4 + j;
                int ch = ct * 32 + cj * 16 + l15;
                S[row * 512 + ((((ch >> 3) ^ (row & 7))) << 3) + (ch & 7)] =
                    f2bf(acc2[rg][cj][j]);
            }
    __syncthreads();
    u16* aop = ao + (size_t)(b * NTOK + mt * 32) * 512;
#pragma unroll
    for (int i = 0; i < 2; i++) {
        int f = i * 1024 + t;             // granule index 0..2047
        int row = f >> 6, g = f & 63;
        uint4 v = *(const uint4*)(S + row * 512 + g * 8);
        *(uint4*)(aop + (size_t)row * 512 + ((g ^ (row & 7)) << 3)) = v;
    }
}

// ---------------------------------------------------------------- launch
extern "C" void kernel_launch(void* const* d_in, const int* in_sizes, int n_in,
                              void* d_out, int out_size, void* d_ws, size_t ws_size,
                              hipStream_t stream) {
    const float* x     = (const float*)d_in[0];
    const float* gamma = (const float*)d_in[1];
    const float* beta  = (const float*)d_in[2];
    const float* Wq    = (const float*)d_in[3];
    const float* bq    = (const float*)d_in[4];
    const float* Wk    = (const float*)d_in[5];
    const float* bk    = (const float*)d_in[6];
    const float* Wv    = (const float*)d_in[7];
    const float* bv    = (const float*)d_in[8];
    const float* Wp    = (const float*)d_in[9];
    const float* bp    = (const float*)d_in[10];
    float* out = (float*)d_out;

    const size_t SZ  = (size_t)MTOT * CH;          // 8,388,608
    const size_t NSZ = (size_t)NTOK * CH;          // per-batch activation

    char* p = (char*)d_ws;
    float*  xn    = (float*)p;   p += SZ * 4;                     // 33.5 MB
    u16*    xnb   = (u16*)p;     p += SZ * 2;                     // 16.8 MB
    u16*    qkvb  = (u16*)p;     p += (size_t)MTOT * 3 * CH * 2;  // 50.3 MB
    u16*    vt    = (u16*)p;     p += SZ * 2;                     // 16.8 MB
    u16*    ao    = (u16*)p;     p += SZ * 2;                     // 16.8 MB
    u16*    WTqkv = (u16*)p;     p += (size_t)3 * CH * CH * 2;    // 1.5 MB
    u16*    WTp   = (u16*)p;     p += (size_t)CH * CH * 2;        // 0.5 MB
    float*  bqkv  = (float*)p;   p += 3 * CH * 4;
    float2* stats = (float2*)p;

    dim3 blk(256);

    gn_stats<<<BATCH * NGRP, blk, 0, stream>>>(x, stats);
    gn_apply<<<2048, blk, 0, stream>>>(x, stats, gamma, beta, xn, xnb);
    weights_prep<<<dim3(8, 8, 4), blk, 0, stream>>>(Wq, Wk, Wv, Wp, WTqkv, WTp);
    prep_bias<<<6, blk, 0, stream>>>(bq, bk, bv, bqkv);

    // fused QKV: [16384x512] @ [512x1536] + bias -> qkvb bf16 (row stride 1536)
    gemm_bt<true, false, false><<<dim3(12, 128, 1), blk, 0, stream>>>(
        xnb, WTqkv, qkvb, bqkv, nullptr, CH, CH, CH, 3 * CH, 0, 0, 0, 1.f);

    // V slice -> V^T per batch
    vt_transpose<<<dim3(8, 16, BATCH), blk, 0, stream>>>(
        qkvb + 2 * CH, vt, NTOK, CH, 3 * CH, (long)NTOK * 3 * CH, (long)NSZ);

    // fused flash attention: scores+softmax+PV -> ao bf16
    attn_fused<<<512, 1024, 0, stream>>>(qkvb, vt, ao);

    // proj + bias + residual(xn f32) -> out f32
    gemm_bt<true, true, true><<<dim3(4, 128, 1), blk, 0, stream>>>(
        ao, WTp, out, bp, xn, CH, CH, CH, CH, 0, 0, 0, 1.f);
}

// Round 10
// 260.093 us; speedup vs baseline: 1.4873x; 1.4873x over previous
//
#include <hip/hip_runtime.h>
#include <math.h>

// Problem constants (B,H,W,C = 16,32,32,512; 32 groups)
#define BATCH 16
#define NTOK  1024
#define CH    512
#define NGRP  32
#define GSZ   16
#define EPSV  1e-3f
#define MTOT  (BATCH*NTOK)          // 16384
#define SCALE 0.04419417382415922f  // 512^-0.5
#define SEXP  (SCALE*1.4426950408889634f)   // scale*log2(e), for exp2

typedef unsigned short u16;
typedef __attribute__((ext_vector_type(4))) float f32x4;
typedef __attribute__((ext_vector_type(8))) short s16x8;

__device__ __forceinline__ u16 f2bf(float f) {           // RNE float->bf16
    union { float f; unsigned u; } x{f};
    unsigned r = x.u + 0x7fff + ((x.u >> 16) & 1);
    return (u16)(r >> 16);
}

__device__ __forceinline__ void gld16(const u16* g, u16* l) {
    __builtin_amdgcn_global_load_lds(
        (const __attribute__((address_space(1))) void*)g,
        (__attribute__((address_space(3))) void*)l, 16, 0, 0);
}

#define MFMA16 __builtin_amdgcn_mfma_f32_16x16x32_bf16

// ---------------------------------------------------------------- group-norm stats
__global__ __launch_bounds__(256) void gn_stats(const float* __restrict__ x,
                                                float2* __restrict__ stats) {
    int bg = blockIdx.x;             // batch*32 + group
    int b = bg >> 5, g = bg & 31;
    const float* base = x + (size_t)b * NTOK * CH + g * GSZ;
    float s = 0.f, ss = 0.f;
    for (int i = threadIdx.x; i < 4096; i += 256) {
        int p = i >> 2, c4 = i & 3;
        float4 v = *(const float4*)(base + (size_t)p * CH + c4 * 4);
        s  += v.x + v.y + v.z + v.w;
        ss += v.x * v.x + v.y * v.y + v.z * v.z + v.w * v.w;
    }
    for (int off = 32; off; off >>= 1) {
        s  += __shfl_down(s, off);
        ss += __shfl_down(ss, off);
    }
    __shared__ float2 part[4];
    if ((threadIdx.x & 63) == 0) part[threadIdx.x >> 6] = make_float2(s, ss);
    __syncthreads();
    if (threadIdx.x == 0) {
        float S = 0.f, SS = 0.f;
        for (int i = 0; i < 4; i++) { S += part[i].x; SS += part[i].y; }
        float mean = S * (1.f / 16384.f);
        float var  = SS * (1.f / 16384.f) - mean * mean;
        stats[bg] = make_float2(mean, rsqrtf(var + EPSV));
    }
}

// ---------------------------------------------------------------- apply norm -> xn(f32) + xnb(bf16)
__global__ __launch_bounds__(256) void gn_apply(const float* __restrict__ x,
                                                const float2* __restrict__ stats,
                                                const float* __restrict__ gamma,
                                                const float* __restrict__ beta,
                                                float* __restrict__ xn,
                                                u16* __restrict__ xnb) {
    size_t total = (size_t)MTOT * CH / 4;
    for (size_t i4 = (size_t)blockIdx.x * 256 + threadIdx.x; i4 < total;
         i4 += (size_t)gridDim.x * 256) {
        size_t flat = i4 * 4;
        int c = (int)(flat & (CH - 1));
        int b = (int)(flat >> 19);
        int g = c >> 4;
        float2 st = stats[(b << 5) + g];
        float4 xv = *(const float4*)(x + flat);
        float4 gv = *(const float4*)(gamma + c);
        float4 bv = *(const float4*)(beta + c);
        float4 o;
        o.x = (xv.x - st.x) * st.y * gv.x + bv.x;
        o.y = (xv.y - st.x) * st.y * gv.y + bv.y;
        o.z = (xv.z - st.x) * st.y * gv.z + bv.z;
        o.w = (xv.w - st.x) * st.y * gv.w + bv.w;
        *(float4*)(xn + flat) = o;
        uint2 h;
        h.x = (unsigned)f2bf(o.x) | ((unsigned)f2bf(o.y) << 16);
        h.y = (unsigned)f2bf(o.z) | ((unsigned)f2bf(o.w) << 16);
        *(uint2*)(xnb + flat) = h;
    }
}

// ---------------------------------------------------------------- weights: transpose f32->bf16, all 4 in one dispatch
__global__ __launch_bounds__(256) void weights_prep(
    const float* __restrict__ Wq, const float* __restrict__ Wk,
    const float* __restrict__ Wv, const float* __restrict__ Wp,
    u16* __restrict__ WTqkv, u16* __restrict__ WTp) {
    int z = blockIdx.z;
    const float* src = z == 0 ? Wq : z == 1 ? Wk : z == 2 ? Wv : Wp;
    u16* dst = z < 3 ? WTqkv + (size_t)z * CH * CH : WTp;
    __shared__ u16 tile[64][66];
    int r0 = blockIdx.y * 64, c0 = blockIdx.x * 64;
    int t = threadIdx.x;
    for (int i = 0; i < 16; i++) {
        int idx = i * 256 + t;
        int r = idx >> 6, c = idx & 63;
        tile[r][c] = f2bf(src[(size_t)(r0 + r) * CH + c0 + c]);
    }
    __syncthreads();
    for (int i = 0; i < 16; i++) {
        int idx = i * 256 + t;
        int oc = idx >> 6, orr = idx & 63;
        dst[(size_t)(c0 + oc) * CH + r0 + orr] = tile[orr][oc];
    }
}

// bias concat [bq|bk|bv] -> bqkv[1536]
__global__ void prep_bias(const float* __restrict__ bq, const float* __restrict__ bk,
                          const float* __restrict__ bv, float* __restrict__ bqkv) {
    int t = blockIdx.x * 256 + threadIdx.x;   // 0..1535
    bqkv[t] = t < 512 ? bq[t] : (t < 1024 ? bk[t - 512] : bv[t - 1024]);
}

// ---------------------------------------------------------------- bf16 MFMA GEMM  (C = alpha*A*B^T (+bias) (+res))
// 128x128 tile, 4 waves, dbuf LDS, 2-phase. Chunked XCD swizzle (nb % 8 == 0).
// VTOUT: columns >=1024 (the V stripe of the QKV gemm) are written TRANSPOSED
// into vtout[b*512+ch][tok] as 8B packs (fuses the old vt_transpose pass).
template <bool BIAS, bool RES, bool OUTF32, bool VTOUT>
__global__ __launch_bounds__(256) void gemm_bt(
    const u16* __restrict__ A, const u16* __restrict__ B, void* __restrict__ Cout,
    const float* __restrict__ bias, const float* __restrict__ res,
    u16* __restrict__ vtout,
    int K, int lda, int ldb, int ldc,
    long sA, long sB, long sC, float alpha) {
    __shared__ __align__(16) u16 Asm[8192];   // 2 x 8 KB
    __shared__ __align__(16) u16 Bsm[8192];

    unsigned flat = blockIdx.x + gridDim.x * (blockIdx.y + gridDim.y * blockIdx.z);
    unsigned nb = gridDim.x * gridDim.y * gridDim.z;
    unsigned lf = (flat & 7) * (nb >> 3) + (flat >> 3);
    unsigned pb = gridDim.x * gridDim.y;
    unsigned bz = lf / pb, rem = lf - bz * pb;
    unsigned by = rem / gridDim.x, bx = rem - by * gridDim.x;

    A += (size_t)bz * sA;
    B += (size_t)bz * sB;
    size_t zc = (size_t)bz * sC;

    int t = threadIdx.x;
    int wave = t >> 6, lane = t & 63;
    int wm = wave >> 1, wn = wave & 1;
    int rowA0 = by * 128;
    int colB0 = bx * 128;

    int c16log = (lane & 3) ^ ((lane >> 3) & 3);     // pre-swizzled global source
    const u16* aG[2]; const u16* bG[2]; u16* aL[2]; u16* bL[2];
#pragma unroll
    for (int j = 0; j < 2; j++) {
        int s = wave * 2 + j;
        int row = s * 16 + (lane >> 2);
        aL[j] = Asm + s * 512;
        bL[j] = Bsm + s * 512;
        aG[j] = A + (size_t)(rowA0 + row) * lda + c16log * 8;
        bG[j] = B + (size_t)(colB0 + row) * ldb + c16log * 8;
    }

    int kg = lane >> 4;
    int aoff[4], boff[4];
#pragma unroll
    for (int i = 0; i < 4; i++) {
        int ra = wm * 64 + i * 16 + (lane & 15);
        aoff[i] = ra * 32 + (kg ^ ((ra >> 1) & 3)) * 8;
        int rb = wn * 64 + i * 16 + (lane & 15);
        boff[i] = rb * 32 + (kg ^ ((rb >> 1) & 3)) * 8;
    }

#define STG_G(buf, ktE)                          \
    {                                            \
        gld16(aG[0] + (ktE), aL[0] + (buf) * 4096); \
        gld16(aG[1] + (ktE), aL[1] + (buf) * 4096); \
        gld16(bG[0] + (ktE), bL[0] + (buf) * 4096); \
        gld16(bG[1] + (ktE), bL[1] + (buf) * 4096); \
    }

    f32x4 acc[4][4] = {};
    int nk = K >> 5;
    STG_G(0, 0);
    __syncthreads();
    for (int kt = 0; kt < nk; kt++) {
        if (kt + 1 < nk) STG_G((kt + 1) & 1, (kt + 1) * 32);
        const u16* as = Asm + (kt & 1) * 4096;
        const u16* bs = Bsm + (kt & 1) * 4096;
        s16x8 af[4], bfr[4];
#pragma unroll
        for (int i = 0; i < 4; i++) {
            af[i]  = *(const s16x8*)(as + aoff[i]);
            bfr[i] = *(const s16x8*)(bs + boff[i]);
        }
#pragma unroll
        for (int mi = 0; mi < 4; mi++)
#pragma unroll
            for (int nj = 0; nj < 4; nj++)
                acc[mi][nj] = MFMA16(af[mi], bfr[nj], acc[mi][nj], 0, 0, 0);
        __syncthreads();
    }
#undef STG_G

    int r0 = rowA0 + wm * 64 + (lane >> 4) * 4;
    int c0c = colB0 + wn * 64 + (lane & 15);
#pragma unroll
    for (int mi = 0; mi < 4; mi++) {
#pragma unroll
        for (int nj = 0; nj < 4; nj++) {
            int c = c0c + nj * 16;
            float bv = BIAS ? bias[c] : 0.f;
            f32x4 v = acc[mi][nj];
            if (VTOUT && c >= 1024) {
                int rr0 = r0 + mi * 16;                 // 4 consecutive rows (tokens)
                int ch = c - 1024, bb = rr0 >> 10, tok = rr0 & 1023;
                ushort4 pk;
                pk.x = f2bf(v[0] * alpha + bv);
                pk.y = f2bf(v[1] * alpha + bv);
                pk.z = f2bf(v[2] * alpha + bv);
                pk.w = f2bf(v[3] * alpha + bv);
                *(ushort4*)(vtout + ((size_t)(bb * 512 + ch)) * 1024 + tok) = pk;
            } else {
#pragma unroll
                for (int j = 0; j < 4; j++) {
                    int rr = r0 + mi * 16 + j;
                    float val = v[j] * alpha + bv;
                    if (RES) val += res[(size_t)rr * ldc + c];
                    if (OUTF32) ((float*)Cout)[zc + (size_t)rr * ldc + c] = val;
                    else        ((u16*)Cout)[zc + (size_t)rr * ldc + c] = f2bf(val);
                }
            }
        }
    }
}

// ---------------------------------------------------------------- fused scores + softmax -> P (bf16)
// One block per (batch, 64-row q-tile). 512 thr = 8 waves as 2 row-teams x 4 col-teams
// (B-frag LDS amplification 2x, was 4x in the r5 4x2 layout).
// Q streamed from L2 per kt; K double-buffered 2x64KB LDS (XOR-swizzled both sides).
__global__ __launch_bounds__(512, 2) void attn_fused(const u16* __restrict__ qkv,
                                                     u16* __restrict__ P) {
    __shared__ __align__(16) u16 S[65536];       // 2 x 64 KB K tiles (reused reduce/pack)

    unsigned flat = blockIdx.x;                  // 256 blocks
    unsigned lf = (flat & 7) * 32 + (flat >> 3); // 2 batches per XCD
    int b = lf >> 4, mt = lf & 15;

    int t = threadIdx.x, w = t >> 6, lane = t & 63;
    int rt = w >> 2, ct = w & 3;                 // row-team 0..1, col-team 0..3
    int l15 = lane & 15, kg = lane >> 4;

    const u16* kbase = qkv + (size_t)b * NTOK * 1536 + CH;
    int c16log = (lane & 3) ^ ((lane >> 3) & 3);

    // K staging: 64 segs of 16 rows; wave w stages segs w*8..w*8+7
    const u16* bG[8];
#pragma unroll
    for (int j = 0; j < 8; j++) {
        int row = (w * 8 + j) * 16 + (lane >> 2);
        bG[j] = kbase + (size_t)row * 1536 + c16log * 8;
    }
    // Q frag pointers (2 row-groups of 16 rows; frags re-read from L2 per kt)
    const u16* qp[2];
#pragma unroll
    for (int rg = 0; rg < 2; rg++)
        qp[rg] = qkv + (size_t)(b * NTOK + mt * 64 + rt * 32 + rg * 16 + l15) * 1536 + kg * 8;

    int rbb = ct * 256 + l15;                    // K B-frag base row (col-team quarter)
    int boffb = rbb * 32 + ((kg ^ ((rbb >> 1) & 3)) << 3);   // nj stride = 512 u16

    f32x4 acc1[2][16];
#pragma unroll
    for (int rg = 0; rg < 2; rg++)
#pragma unroll
        for (int nj = 0; nj < 16; nj++) acc1[rg][nj] = f32x4{0.f, 0.f, 0.f, 0.f};

#define KSTG(buf, kt)                                                        \
    { _Pragma("unroll")                                                      \
      for (int j = 0; j < 8; j++)                                            \
          gld16(bG[j] + (kt) * 32, S + (buf) * 32768 + (w * 8 + j) * 512); }

    KSTG(0, 0);
    s16x8 aqc[2], aqn[2];
    aqc[0] = *(const s16x8*)(qp[0]);
    aqc[1] = *(const s16x8*)(qp[1]);
    __syncthreads();
#pragma unroll
    for (int kt = 0; kt < 16; kt++) {
        if (kt < 15) {
            KSTG((kt + 1) & 1, kt + 1);
            aqn[0] = *(const s16x8*)(qp[0] + (kt + 1) * 32);
            aqn[1] = *(const s16x8*)(qp[1] + (kt + 1) * 32);
        }
        const u16* bb = S + (kt & 1) * 32768;
        __builtin_amdgcn_s_setprio(1);
#pragma unroll
        for (int nj = 0; nj < 16; nj++) {
            s16x8 bf = *(const s16x8*)(bb + boffb + nj * 512);
            acc1[0][nj] = MFMA16(aqc[0], bf, acc1[0][nj], 0, 0, 0);
            acc1[1][nj] = MFMA16(aqc[1], bf, acc1[1][nj], 0, 0, 0);
        }
        __builtin_amdgcn_s_setprio(0);
        if (kt < 15) { aqc[0] = aqn[0]; aqc[1] = aqn[1]; }
        __syncthreads();
    }
#undef KSTG

    // ---- softmax over full 1024 cols (4 col-teams; scale folded into exp2) ----
    float* redm = (float*)S;          // [64][4]
    float* reds = redm + 256;         // [64][4]
    float mr[2][4], iv[2][4];
#pragma unroll
    for (int rg = 0; rg < 2; rg++)
#pragma unroll
        for (int j = 0; j < 4; j++) {
            float m = acc1[rg][0][j];
#pragma unroll
            for (int nj = 1; nj < 16; nj++) m = fmaxf(m, acc1[rg][nj][j]);
            for (int off = 1; off < 16; off <<= 1) m = fmaxf(m, __shfl_xor(m, off));
            mr[rg][j] = m;
        }
    if (l15 == 0) {
#pragma unroll
        for (int rg = 0; rg < 2; rg++)
#pragma unroll
            for (int j = 0; j < 4; j++)
                redm[(rt * 32 + rg * 16 + kg * 4 + j) * 4 + ct] = mr[rg][j];
    }
    __syncthreads();
#pragma unroll
    for (int rg = 0; rg < 2; rg++)
#pragma unroll
        for (int j = 0; j < 4; j++) {
            int row = rt * 32 + rg * 16 + kg * 4 + j;
            mr[rg][j] = fmaxf(fmaxf(redm[row * 4], redm[row * 4 + 1]),
                              fmaxf(redm[row * 4 + 2], redm[row * 4 + 3]));
        }
#pragma unroll
    for (int rg = 0; rg < 2; rg++)
#pragma unroll
        for (int j = 0; j < 4; j++) {
            float s = 0.f;
#pragma unroll
            for (int nj = 0; nj < 16; nj++) {
                float e = exp2f((acc1[rg][nj][j] - mr[rg][j]) * SEXP);
                acc1[rg][nj][j] = e;
                s += e;
            }
            for (int off = 1; off < 16; off <<= 1) s += __shfl_xor(s, off);
            if (l15 == 0) reds[(rt * 32 + rg * 16 + kg * 4 + j) * 4 + ct] = s;
        }
    __syncthreads();
#pragma unroll
    for (int rg = 0; rg < 2; rg++)
#pragma unroll
        for (int j = 0; j < 4; j++) {
            int row = rt * 32 + rg * 16 + kg * 4 + j;
            iv[rg][j] = 1.f / (reds[row * 4] + reds[row * 4 + 1] +
                               reds[row * 4 + 2] + reds[row * 4 + 3]);
        }
    __syncthreads();   // reduce reads done before pack overwrites S

    // ---- pack P (bf16) through LDS, one 64x512 half at a time ----
    size_t pbase = (size_t)b * NTOK * NTOK + (size_t)mt * 64 * NTOK;
#pragma unroll
    for (int h = 0; h < 2; h++) {
        __syncthreads();     // previous users of S done
        if ((ct >> 1) == h) {            // col-teams {2h, 2h+1} own half h
#pragma unroll
            for (int rg = 0; rg < 2; rg++)
#pragma unroll
                for (int nj = 0; nj < 16; nj++) {
                    int c = (ct & 1) * 256 + nj * 16 + l15;   // col within half
                    int c16 = c >> 3, cw = c & 7;
#pragma unroll
                    for (int j = 0; j < 4; j++) {
                        int row = rt * 32 + rg * 16 + kg * 4 + j;
                        int pc16 = c16 ^ ((row >> 2) & 7);
                        S[row * 512 + pc16 * 8 + cw] = f2bf(acc1[rg][nj][j] * iv[rg][j]);
                    }
                }
        }
        __syncthreads();
#pragma unroll
        for (int i = 0; i < 8; i++) {
            int flat16 = (i * 512 + t) * 8;
            int row = flat16 >> 9, c = flat16 & 511;
            int pc16 = (c >> 3) ^ ((row >> 2) & 7);
            uint4 vv = *(const uint4*)(S + row * 512 + pc16 * 8);
            *(uint4*)(P + pbase + (size_t)row * NTOK + h * 512 + c) = vv;
        }
    }
}

// ---------------------------------------------------------------- launch
extern "C" void kernel_launch(void* const* d_in, const int* in_sizes, int n_in,
                              void* d_out, int out_size, void* d_ws, size_t ws_size,
                              hipStream_t stream) {
    const float* x     = (const float*)d_in[0];
    const float* gamma = (const float*)d_in[1];
    const float* beta  = (const float*)d_in[2];
    const float* Wq    = (const float*)d_in[3];
    const float* bq    = (const float*)d_in[4];
    const float* Wk    = (const float*)d_in[5];
    const float* bk    = (const float*)d_in[6];
    const float* Wv    = (const float*)d_in[7];
    const float* bv    = (const float*)d_in[8];
    const float* Wp    = (const float*)d_in[9];
    const float* bp    = (const float*)d_in[10];
    float* out = (float*)d_out;

    const size_t SZ  = (size_t)MTOT * CH;          // 8,388,608
    const size_t NSZ = (size_t)NTOK * CH;          // per-batch activation
    const size_t SCB = (size_t)NTOK * NTOK;        // per-batch P

    char* p = (char*)d_ws;
    float*  xn    = (float*)p;   p += SZ * 4;                     // 33.5 MB
    u16*    xnb   = (u16*)p;     p += SZ * 2;                     // 16.8 MB
    u16*    qkvb  = (u16*)p;     p += (size_t)MTOT * 3 * CH * 2;  // 50.3 MB
    u16*    vt    = (u16*)p;     p += SZ * 2;                     // 16.8 MB
    u16*    ao    = (u16*)p;     p += SZ * 2;                     // 16.8 MB
    u16*    P     = (u16*)p;     p += (size_t)BATCH * SCB * 2;    // 33.5 MB
    u16*    WTqkv = (u16*)p;     p += (size_t)3 * CH * CH * 2;    // 1.5 MB
    u16*    WTp   = (u16*)p;     p += (size_t)CH * CH * 2;        // 0.5 MB
    float*  bqkv  = (float*)p;   p += 3 * CH * 4;
    float2* stats = (float2*)p;

    dim3 blk(256);

    gn_stats<<<BATCH * NGRP, blk, 0, stream>>>(x, stats);
    gn_apply<<<2048, blk, 0, stream>>>(x, stats, gamma, beta, xn, xnb);
    weights_prep<<<dim3(8, 8, 4), blk, 0, stream>>>(Wq, Wk, Wv, Wp, WTqkv, WTp);
    prep_bias<<<6, blk, 0, stream>>>(bq, bk, bv, bqkv);

    // fused QKV: [16384x512] @ [512x1536] + bias -> q,k into qkvb; V stripe
    // written TRANSPOSED into vt (per batch [512][1024]) by the epilogue.
    gemm_bt<true, false, false, true><<<dim3(12, 128, 1), blk, 0, stream>>>(
        xnb, WTqkv, qkvb, bqkv, nullptr, vt, CH, CH, CH, 3 * CH, 0, 0, 0, 1.f);

    // fused scores+softmax -> P bf16
    attn_fused<<<256, 512, 0, stream>>>(qkvb, P);

    // out_attn = P @ V (batched): A=P [1024x1024], B=vt [512][1024] -> ao bf16
    gemm_bt<false, false, false, false><<<dim3(4, 8, BATCH), blk, 0, stream>>>(
        P, vt, ao, nullptr, nullptr, nullptr, NTOK, NTOK, NTOK, CH,
        (long)SCB, (long)NSZ, (long)NSZ, 1.f);

    // proj + bias + residual(xn f32) -> out f32
    gemm_bt<true, true, true, false><<<dim3(4, 128, 1), blk, 0, stream>>>(
        ao, WTp, out, bp, xn, nullptr, CH, CH, CH, CH, 0, 0, 0, 1.f);
}